// Round 11
// baseline (193.479 us; speedup 1.0000x reference)
//
#include <hip/hip_runtime.h>

typedef unsigned short u16;
typedef unsigned int u32;
typedef __bf16 bf16x8 __attribute__((ext_vector_type(8)));
typedef float f32x4 __attribute__((ext_vector_type(4)));
typedef u16 u16x4 __attribute__((ext_vector_type(4)));
typedef u16 u16x8 __attribute__((ext_vector_type(8)));

#define GL2LDS16(g, l)                                                         \
    __builtin_amdgcn_global_load_lds(                                          \
        (__attribute__((address_space(1))) const void*)(g),                    \
        (__attribute__((address_space(3))) void*)(l), 16, 0, 0)

#define SYNC_VM(n) asm volatile("s_waitcnt vmcnt(" #n ")\ns_barrier" ::: "memory")
#define BAR()      asm volatile("s_barrier" ::: "memory")
// DS-draining barrier (R7 lesson): required when one wave's LDS writes must be
// visible to another wave's reads, or before clobbering LDS others may read.
#define BAR_DS()   asm volatile("s_waitcnt lgkmcnt(0)\ns_barrier" ::: "memory")

// ---------- helpers ----------
__device__ __forceinline__ u16 f2bf(float f) {
    union { float f; u32 u; } x; x.f = f;
    u32 r = x.u + 0x7FFFu + ((x.u >> 16) & 1u);   // RNE (no NaNs here)
    return (u16)(r >> 16);
}

// pack 2 floats -> 2 bf16 in one u32 (round-half-up; lo=f0, hi=f1)
__device__ __forceinline__ u32 pack2bf(float f0, float f1) {
    union { float f; u32 u; } a, b;
    a.f = f0; b.f = f1;
    return __builtin_amdgcn_perm(b.u + 0x8000u, a.u + 0x8000u, 0x07060302u);
}

// raw v_exp_f32 (2^x)
__device__ __forceinline__ float fast_exp2(float x) {
    float r;
    asm("v_exp_f32 %0, %1" : "=v"(r) : "v"(x));
    return r;
}

// fold softmax scale * log2(e) into Q fragments (scores then used with exp2)
__device__ __forceinline__ bf16x8 scale_frag(bf16x8 v) {
#pragma unroll
    for (int i = 0; i < 8; ++i) v[i] = (__bf16)((float)v[i] * 0.1803368801f);
    return v;
}

// ---------- fused fp32 -> bf16 convert (x | qkv | wo -> contiguous ws) ----------
__global__ __launch_bounds__(256) void convert_all_kernel(const float* __restrict__ x,
                                                          const float* __restrict__ qkv,
                                                          const float* __restrict__ wo,
                                                          u16* __restrict__ out) {
    int i = (blockIdx.x * 256 + threadIdx.x) * 4;
    const float* src;
    int off;
    if (i < 4194304)      { src = x;   off = i; }
    else if (i < 7340032) { src = qkv; off = i - 4194304; }
    else                  { src = wo;  off = i - 7340032; }
    float4 v = *(const float4*)(src + off);
    u16x4 o;
    o.x = f2bf(v.x); o.y = f2bf(v.y); o.z = f2bf(v.z); o.w = f2bf(v.w);
    *(u16x4*)(out + i) = o;
}

// ---------- GEMM: C[M,N] = A[M,K] * B[N,K]^T, bf16, double-buffered pipeline ----------
// FUSE_VT: blocks with n0 >= 2048 (V columns of the QKV projection) write ONLY
// the transposed copy VtG[(b*16+h)*64+dh][s], via an LDS transpose (reusing the
// staging buffer) so global stores are 256B coalesced u16x8 along s (R9 win).
template <int TM, bool OUT_BF16, bool FUSE_VT>
__global__ __launch_bounds__(256) void gemm_bt(const u16* __restrict__ A,
                                               const u16* __restrict__ B,
                                               void* __restrict__ Cout,
                                               u16* __restrict__ VtG,
                                               int M, int N, int K) {
    constexpr int MI = TM / 32;
    // single LDS pool: As = SM[0 .. 2*TM*32), Bs = SM[2*TM*32 ..).
    // For TM=128 the pool is exactly 32KB = the 128x128 bf16 epilogue tile.
    __shared__ u16 SM[2 * TM * 32 + 2 * 128 * 32];
    u16* Asm = SM;
    u16* Bsm = SM + 2 * TM * 32;
    const int tid = threadIdx.x;
    const int w = tid >> 6, lane = tid & 63, ln = lane & 15, qd = lane >> 4;
    const int wr = w >> 1, wc = w & 1;
    const int m0 = blockIdx.y * TM, n0 = blockIdx.x * 128;

    const int srow = tid >> 2, scol = (tid & 3) * 8;
    const u16* Abase = A + (size_t)(m0 + srow) * K + scol;
    const u16* Bbase = B + (size_t)(n0 + srow) * K + scol;

    f32x4 acc[MI][4] = {};
    const int nsteps = K >> 5;

#pragma unroll
    for (int it = 0; it < TM / 64; ++it)
        GL2LDS16(Abase + (size_t)(it * 64) * K, &Asm[(tid + it * 256) * 8]);
#pragma unroll
    for (int it = 0; it < 2; ++it)
        GL2LDS16(Bbase + (size_t)(it * 64) * K, &Bsm[(tid + it * 256) * 8]);

    for (int s = 0; s < nsteps; ++s) {
        const u16* Ab = &Asm[(s & 1) * TM * 32];
        const u16* Bb = &Bsm[(s & 1) * 128 * 32];
        if (s + 1 < nsteps) {
            const int nk = (s + 1) << 5;
            const int nb = (s + 1) & 1;
#pragma unroll
            for (int it = 0; it < TM / 64; ++it)
                GL2LDS16(Abase + (size_t)(it * 64) * K + nk, &Asm[nb * TM * 32 + (tid + it * 256) * 8]);
#pragma unroll
            for (int it = 0; it < 2; ++it)
                GL2LDS16(Bbase + (size_t)(it * 64) * K + nk, &Bsm[nb * 128 * 32 + (tid + it * 256) * 8]);
            if constexpr (TM == 128) SYNC_VM(4); else SYNC_VM(3);
        } else {
            SYNC_VM(0);
        }

        bf16x8 af[MI], bfr[4];
#pragma unroll
        for (int i = 0; i < MI; ++i)
            af[i] = *(const bf16x8*)&Ab[(wr * (TM / 2) + i * 16 + ln) * 32 + qd * 8];
#pragma unroll
        for (int j = 0; j < 4; ++j)
            bfr[j] = *(const bf16x8*)&Bb[(wc * 64 + j * 16 + ln) * 32 + qd * 8];
        __builtin_amdgcn_s_setprio(1);
#pragma unroll
        for (int i = 0; i < MI; ++i)
#pragma unroll
            for (int j = 0; j < 4; ++j)
                acc[i][j] = __builtin_amdgcn_mfma_f32_16x16x32_bf16(af[i], bfr[j], acc[i][j], 0, 0, 0);
        __builtin_amdgcn_s_setprio(0);
        BAR();
    }

    if constexpr (FUSE_VT) {
        if (n0 >= 2048) {
            // ---- LDS-transpose epilogue for coalesced VtG stores ----
            const int bq = m0 >> 11;
            BAR_DS();                      // drain all ds_reads of staging data
#pragma unroll
            for (int i = 0; i < MI; ++i)
#pragma unroll
                for (int j = 0; j < 4; ++j) {
                    int col = wc * 64 + j * 16 + ln;
                    int row0 = wr * 64 + i * 16 + qd * 4;
                    int pr = row0 ^ (((col >> 2) & 3) << 4);
                    u16x4 ov;
                    ov.x = f2bf(acc[i][j][0]); ov.y = f2bf(acc[i][j][1]);
                    ov.z = f2bf(acc[i][j][2]); ov.w = f2bf(acc[i][j][3]);
                    *(u16x4*)&SM[col * 128 + pr] = ov;
                }
            BAR_DS();                      // writes visible before cross-wave reads
#pragma unroll
            for (int p = 0; p < 8; ++p) {
                int flat = p * 2048 + tid * 8;
                int colL = flat >> 7, rowL = flat & 127;
                int pr = rowL ^ (((colL >> 2) & 3) << 4);
                u16x8 v = *(const u16x8*)&SM[colL * 128 + pr];
                int d = n0 - 2048 + colL;
                int vrow = (bq * 16 + (d >> 6)) * 64 + (d & 63);
                *(u16x8*)&VtG[(size_t)vrow * 2048 + (m0 & 2047) + rowL] = v;
            }
            return;
        }
    }

#pragma unroll
    for (int i = 0; i < MI; ++i)
#pragma unroll
        for (int j = 0; j < 4; ++j)
#pragma unroll
            for (int r = 0; r < 4; ++r) {
                int row = m0 + wr * (TM / 2) + i * 16 + qd * 4 + r;
                int col = n0 + wc * 64 + j * 16 + ln;
                float v = acc[i][j][r];
                if constexpr (OUT_BF16)
                    ((u16*)Cout)[(size_t)row * N + col] = f2bf(v);
                else
                    ((float*)Cout)[(size_t)row * N + col] = v;
            }
}

// ---------- flash attention (causal): permuted-K register-P + helper waves ----------
// R10 base (45.8us, 0 bank conflicts): uniform pairs (t,63-t), pi-permuted K
// staging makes the PV B-frag materialize directly in score registers (zero
// P LDS / cross-lane), GL2LDS double-buffered K/V, no-max exp2 softmax.
// R11 change: light waves (2,3), after finishing their tile at c = nchL, HELP
// the heavy tile: for c in [nchL, nchH) the 64 keys split by half — waves 0-1
// keys 0-31 (kt pair {0,1}, V colgroup qd), waves 2-3 keys 32-63 (kt {2,3},
// colgroup qd+4) on heavy q rows (w&1)*16. Disjoint-key partials (o,l) add;
// heavy halves combined once via LDS scratch (BAR_DS discipline, R8-verified).
// Work per block becomes uniform 16.5 full-epoch-equivalents for EVERY t
// (nchL + (nchH-nchL)/2), zero idle wave-slots. Mode switch (c < nchL) is
// block-uniform; accumulator selection via wave-uniform branches (rule #20).
__global__ __launch_bounds__(256) void attn_kernel(const u16* __restrict__ QKV,
                                                   const u16* __restrict__ VtG,
                                                   u16* __restrict__ AO) {
    __shared__ u16 Ks[2][64 * 64];     // [stored-key(pi-permuted)][dh], swizzled; scratch at end
    __shared__ u16 Vts[2][64 * 64];    // [dh][key natural], swizzled; l scratch at end

    const int tid = threadIdx.x;
    const int w = tid >> 6, lane = tid & 63, ln = lane & 15, qd = lane >> 4;
    const int b = blockIdx.z, h = blockIdx.y;
    const int t = blockIdx.x;              // pair index 0..31 (heavy-first order)
    const int tH = 63 - t;
    const bool heavy = (w < 2);
    const int wq = w & 1;
    const int bh = b * 16 + h;
    const int swz = ln & 7;
    const int nchH = (tH >> 1) + 1;        // 17..32
    const int nchL = (t >> 1) + 1;         // 1..16 (always < nchH)
    const int myqH = tH * 32 + wq * 16 + ln;
    const int myqL = t * 32 + wq * 16 + ln;
    const int myqA = heavy ? myqH : myqL;  // own-tile q row (full phase)

    // staging: LDS slot row = sr0, swizzled colgroup; K source row = pi(sr0):
    // LDS row (h,Q1,Q0,r1,r0) <- key (Q1,Q0,h,r1,r0)  (R10-verified).
    const int sr0 = tid >> 3;
    const int srP = ((sr0 >> 2) & 3) * 8 + ((sr0 >> 4) & 1) * 4 + (sr0 & 3);
    const int sg = (tid & 7) ^ (sr0 & 7);
    const u16* ksrc = QKV + (size_t)(b * 2048 + srP) * 3072 + 1024 + h * 64 + sg * 8;
    const u16* vsrc = VtG + (size_t)(bh * 64 + sr0) * 2048 + sg * 8;

    GL2LDS16(ksrc, &Ks[0][tid * 8]);
    GL2LDS16(ksrc + (size_t)32 * 3072, &Ks[0][tid * 8 + 2048]);
    GL2LDS16(vsrc, &Vts[0][tid * 8]);
    GL2LDS16(vsrc + (size_t)32 * 2048, &Vts[0][tid * 8 + 2048]);

    // Q B-frags: own tile (full phase) + heavy rows wq*16 (helper phase).
    const u16* qpA = QKV + (size_t)(b * 2048 + myqA) * 3072 + h * 64;
    const u16* qpH = QKV + (size_t)(b * 2048 + myqH) * 3072 + h * 64;
    bf16x8 qfa0 = scale_frag(*(const bf16x8*)(qpA + qd * 8));
    bf16x8 qfa1 = scale_frag(*(const bf16x8*)(qpA + 32 + qd * 8));
    bf16x8 qfh0 = scale_frag(*(const bf16x8*)(qpH + qd * 8));
    bf16x8 qfh1 = scale_frag(*(const bf16x8*)(qpH + 32 + qd * 8));

    f32x4 oA[4] = {};    // own tile (w01: heavy incl. helper keys 0-31; w23: light)
    f32x4 oH2[4] = {};   // w23 only: heavy rows wq*16, keys 32-63 of helper chunks
    float lA = 0.f, lH2 = 0.f;

    for (int c = 0; c < nchH; ++c) {
        if (c + 1 < nchH) {
            const int k1 = (c + 1) * 64;
            const int nb = (c + 1) & 1;
            GL2LDS16(ksrc + (size_t)k1 * 3072, &Ks[nb][tid * 8]);
            GL2LDS16(ksrc + (size_t)(k1 + 32) * 3072, &Ks[nb][tid * 8 + 2048]);
            GL2LDS16(vsrc + k1, &Vts[nb][tid * 8]);
            GL2LDS16(vsrc + k1 + 32 * 2048, &Vts[nb][tid * 8 + 2048]);
            SYNC_VM(4);
        } else {
            SYNC_VM(0);
        }
        const u16* Kb = Ks[c & 1];
        const u16* Vb = Vts[c & 1];

        if (c < nchL) {
            // ---- FULL phase: own tile, all 64 keys ----
            f32x4 s[4];
            __builtin_amdgcn_s_setprio(1);
#pragma unroll
            for (int kt = 0; kt < 4; ++kt) {
                const u16* kr = Kb + (kt * 16 + ln) * 64;
                bf16x8 kf0 = *(const bf16x8*)(kr + ((qd ^ swz) * 8));
                bf16x8 kf1 = *(const bf16x8*)(kr + (((qd + 4) ^ swz) * 8));
                f32x4 z = {0.f, 0.f, 0.f, 0.f};
                z = __builtin_amdgcn_mfma_f32_16x16x32_bf16(kf0, qfa0, z, 0, 0, 0);
                z = __builtin_amdgcn_mfma_f32_16x16x32_bf16(kf1, qfa1, z, 0, 0, 0);
                s[kt] = z;
            }
            __builtin_amdgcn_s_setprio(0);

            // light diagonal only (heavy diag is always >= nchL -> helper phase)
            if (!heavy && c == nchL - 1) {
#pragma unroll
                for (int kt = 0; kt < 4; ++kt)
#pragma unroll
                    for (int r = 0; r < 4; ++r) {
                        int key = c * 64 + 32 * (kt >> 1) + 8 * qd + 4 * (kt & 1) + r;
                        if (key > myqL) s[kt][r] = -1e30f;
                    }
            }

            bf16x8 pf0, pf1;
#pragma unroll
            for (int kt = 0; kt < 4; ++kt)
#pragma unroll
                for (int r = 0; r < 4; ++r) {
                    float p = fast_exp2(s[kt][r]);
                    lA += p;
                    if (kt < 2) pf0[(kt & 1) * 4 + r] = (__bf16)p;
                    else        pf1[(kt & 1) * 4 + r] = (__bf16)p;
                }

            __builtin_amdgcn_s_setprio(1);
#pragma unroll
            for (int dt = 0; dt < 4; ++dt) {
                const u16* vr = Vb + (dt * 16 + ln) * 64;
                bf16x8 vf0 = *(const bf16x8*)(vr + ((qd ^ swz) * 8));
                bf16x8 vf1 = *(const bf16x8*)(vr + (((qd + 4) ^ swz) * 8));
                oA[dt] = __builtin_amdgcn_mfma_f32_16x16x32_bf16(vf0, pf0, oA[dt], 0, 0, 0);
                oA[dt] = __builtin_amdgcn_mfma_f32_16x16x32_bf16(vf1, pf1, oA[dt], 0, 0, 0);
            }
            __builtin_amdgcn_s_setprio(0);
        } else {
            // ---- HELPER phase: heavy tile, key half kh (w01: 0-31, w23: 32-63) ----
            const int kh = heavy ? 0 : 1;
            f32x4 s2[2];
            __builtin_amdgcn_s_setprio(1);
#pragma unroll
            for (int ktl = 0; ktl < 2; ++ktl) {
                const u16* kr = Kb + ((2 * kh + ktl) * 16 + ln) * 64;
                bf16x8 kf0 = *(const bf16x8*)(kr + ((qd ^ swz) * 8));
                bf16x8 kf1 = *(const bf16x8*)(kr + (((qd + 4) ^ swz) * 8));
                f32x4 z = {0.f, 0.f, 0.f, 0.f};
                z = __builtin_amdgcn_mfma_f32_16x16x32_bf16(kf0, qfh0, z, 0, 0, 0);
                z = __builtin_amdgcn_mfma_f32_16x16x32_bf16(kf1, qfh1, z, 0, 0, 0);
                s2[ktl] = z;
            }
            __builtin_amdgcn_s_setprio(0);

            if (c == nchH - 1) {   // heavy diagonal
#pragma unroll
                for (int ktl = 0; ktl < 2; ++ktl)
#pragma unroll
                    for (int r = 0; r < 4; ++r) {
                        int key = c * 64 + 32 * kh + 8 * qd + 4 * ktl + r;
                        if (key > myqH) s2[ktl][r] = -1e30f;
                    }
            }

            bf16x8 pf;
            float lacc = 0.f;
#pragma unroll
            for (int ktl = 0; ktl < 2; ++ktl)
#pragma unroll
                for (int r = 0; r < 4; ++r) {
                    float p = fast_exp2(s2[ktl][r]);
                    lacc += p;
                    pf[ktl * 4 + r] = (__bf16)p;
                }

            bf16x8 vfh[4];
#pragma unroll
            for (int dt = 0; dt < 4; ++dt)
                vfh[dt] = *(const bf16x8*)&Vb[(dt * 16 + ln) * 64 + (((qd + 4 * kh) ^ swz) * 8)];

            if (heavy) {           // wave-uniform branch: accumulators stay in regs
                lA += lacc;
                __builtin_amdgcn_s_setprio(1);
#pragma unroll
                for (int dt = 0; dt < 4; ++dt)
                    oA[dt] = __builtin_amdgcn_mfma_f32_16x16x32_bf16(vfh[dt], pf, oA[dt], 0, 0, 0);
                __builtin_amdgcn_s_setprio(0);
            } else {
                lH2 += lacc;
                __builtin_amdgcn_s_setprio(1);
#pragma unroll
                for (int dt = 0; dt < 4; ++dt)
                    oH2[dt] = __builtin_amdgcn_mfma_f32_16x16x32_bf16(vfh[dt], pf, oH2[dt], 0, 0, 0);
                __builtin_amdgcn_s_setprio(0);
            }
        }
        BAR();
    }

    // ---- epilogue: reduce l, combine heavy halves via scratch, store ----
    lA += __shfl_xor(lA, 16); lA += __shfl_xor(lA, 32);
    lH2 += __shfl_xor(lH2, 16); lH2 += __shfl_xor(lH2, 32);
    BAR_DS();                              // WAR: drain K/V ds_reads before clobber
    float* scrO = (float*)&Ks[0][0];       // 2 slots x 64 lanes x 20 f32 = 10KB
    float* scrL = (float*)&Vts[0][0];
    if (!heavy) {
#pragma unroll
        for (int dt = 0; dt < 4; ++dt)
            *(f32x4*)&scrO[(wq * 64 + lane) * 20 + dt * 4] = oH2[dt];
        scrL[wq * 64 + lane] = lH2;
    }
    BAR_DS();                              // RAW: writer ds_writes visible
    if (heavy) {
        lA += scrL[wq * 64 + lane];
        float inv = 1.0f / lA;
#pragma unroll
        for (int dt = 0; dt < 4; ++dt) {
            f32x4 s2v = *(const f32x4*)&scrO[(wq * 64 + lane) * 20 + dt * 4];
            uint2 ov = {pack2bf((oA[dt][0] + s2v[0]) * inv, (oA[dt][1] + s2v[1]) * inv),
                        pack2bf((oA[dt][2] + s2v[2]) * inv, (oA[dt][3] + s2v[3]) * inv)};
            *(uint2*)&AO[(size_t)(b * 2048 + myqH) * 1024 + h * 64 + dt * 16 + qd * 4] = ov;
        }
    } else {
        float inv = 1.0f / lA;
#pragma unroll
        for (int dt = 0; dt < 4; ++dt) {
            uint2 ov = {pack2bf(oA[dt][0] * inv, oA[dt][1] * inv),
                        pack2bf(oA[dt][2] * inv, oA[dt][3] * inv)};
            *(uint2*)&AO[(size_t)(b * 2048 + myqL) * 1024 + h * 64 + dt * 16 + qd * 4] = ov;
        }
    }
}

// ---------- launch ----------
extern "C" void kernel_launch(void* const* d_in, const int* in_sizes, int n_in,
                              void* d_out, int out_size, void* d_ws, size_t ws_size,
                              hipStream_t stream) {
    const float* x   = (const float*)d_in[0];   // [2,2048,1024]
    const float* qkv = (const float*)d_in[1];   // [3072,1024]
    const float* wo  = (const float*)d_in[2];   // [1024,1024]
    float* out = (float*)d_out;                 // [2,2048,1024] fp32

    char* ws = (char*)d_ws;
    u16* xb    = (u16*)(ws + 0);            //  8 MB : x bf16 [4096,1024]
    u16* qkvb  = (u16*)(ws + 8388608);      //  6 MB : qkv bf16 [3072,1024]
    u16* wob   = (u16*)(ws + 14680064);     //  2 MB : wo bf16 [1024,1024]
    u16* QKVo  = (u16*)(ws + 16777216);     // 24 MB : QKV bf16 (V-cols unwritten)
    u16* AO    = (u16*)(ws + 41943040);     //  8 MB : attn out [4096,1024]
    u16* VtG   = (u16*)(ws + 50331648);     //  8 MB : V^T [2*16*64, 2048]

    convert_all_kernel<<<8192, 256, 0, stream>>>(x, qkv, wo, xb);

    gemm_bt<128, true, true><<<dim3(24, 32), 256, 0, stream>>>(xb, qkvb, QKVo, VtG,
                                                               4096, 3072, 1024);

    attn_kernel<<<dim3(32, 16, 2), 256, 0, stream>>>(QKVo, VtG, AO);

    gemm_bt<64, false, false><<<dim3(8, 64), 256, 0, stream>>>(AO, wob, out, nullptr,
                                                               4096, 1024, 1024);
}

// Round 12
// 184.612 us; speedup vs baseline: 1.0480x; 1.0480x over previous
//
#include <hip/hip_runtime.h>

typedef unsigned short u16;
typedef unsigned int u32;
typedef __bf16 bf16x8 __attribute__((ext_vector_type(8)));
typedef float f32x4 __attribute__((ext_vector_type(4)));
typedef u16 u16x4 __attribute__((ext_vector_type(4)));
typedef u16 u16x8 __attribute__((ext_vector_type(8)));

#define GL2LDS16(g, l)                                                         \
    __builtin_amdgcn_global_load_lds(                                          \
        (__attribute__((address_space(1))) const void*)(g),                    \
        (__attribute__((address_space(3))) void*)(l), 16, 0, 0)

#define SYNC_VM(n) asm volatile("s_waitcnt vmcnt(" #n ")\ns_barrier" ::: "memory")
#define BAR()      asm volatile("s_barrier" ::: "memory")
// DS-draining barrier (R7 lesson): required when one wave's LDS writes must be
// visible to another wave's reads, or before clobbering LDS others may read.
#define BAR_DS()   asm volatile("s_waitcnt lgkmcnt(0)\ns_barrier" ::: "memory")

// ---------- helpers ----------
__device__ __forceinline__ u16 f2bf(float f) {
    union { float f; u32 u; } x; x.f = f;
    u32 r = x.u + 0x7FFFu + ((x.u >> 16) & 1u);   // RNE (no NaNs here)
    return (u16)(r >> 16);
}

// pack 2 floats -> 2 bf16 in one u32 (round-half-up; lo=f0, hi=f1)
__device__ __forceinline__ u32 pack2bf(float f0, float f1) {
    union { float f; u32 u; } a, b;
    a.f = f0; b.f = f1;
    return __builtin_amdgcn_perm(b.u + 0x8000u, a.u + 0x8000u, 0x07060302u);
}

// raw v_exp_f32 (2^x)
__device__ __forceinline__ float fast_exp2(float x) {
    float r;
    asm("v_exp_f32 %0, %1" : "=v"(r) : "v"(x));
    return r;
}

// fold softmax scale * log2(e) into Q fragments (scores then used with exp2)
__device__ __forceinline__ bf16x8 scale_frag(bf16x8 v) {
#pragma unroll
    for (int i = 0; i < 8; ++i) v[i] = (__bf16)((float)v[i] * 0.1803368801f);
    return v;
}

// ---------- fused fp32 -> bf16 convert (x | qkv | wo -> contiguous ws) ----------
__global__ __launch_bounds__(256) void convert_all_kernel(const float* __restrict__ x,
                                                          const float* __restrict__ qkv,
                                                          const float* __restrict__ wo,
                                                          u16* __restrict__ out) {
    int i = (blockIdx.x * 256 + threadIdx.x) * 4;
    const float* src;
    int off;
    if (i < 4194304)      { src = x;   off = i; }
    else if (i < 7340032) { src = qkv; off = i - 4194304; }
    else                  { src = wo;  off = i - 7340032; }
    float4 v = *(const float4*)(src + off);
    u16x4 o;
    o.x = f2bf(v.x); o.y = f2bf(v.y); o.z = f2bf(v.z); o.w = f2bf(v.w);
    *(u16x4*)(out + i) = o;
}

// ---------- GEMM: C[M,N] = A[M,K] * B[N,K]^T, bf16, double-buffered pipeline ----------
// SWAP: operand-swapped MFMA (mfma(bfr, af, acc) — frag layouts are symmetric,
// same trick as attn's S^T = K Q^T). Output transposes so a thread's 4 acc
// values land in 4 CONSECUTIVE COLUMNS -> packed u16x4/f32x4 stores (16 store
// instrs/thread instead of 64 scalars; full-sector writes). R12 change.
// FUSE_VT: this kernel instance computes ONLY the V columns (B pre-offset by
// 2048 rows, n0 local in [0,1024)) and writes the transposed copy
// VtG[(b*16+h)*64+dh][s] via the R9 LDS-transpose epilogue (old orientation).
template <int TM, bool OUT_BF16, bool FUSE_VT, bool SWAP>
__global__ __launch_bounds__(256) void gemm_bt(const u16* __restrict__ A,
                                               const u16* __restrict__ B,
                                               void* __restrict__ Cout,
                                               u16* __restrict__ VtG,
                                               int M, int N, int K) {
    constexpr int MI = TM / 32;
    // single LDS pool: As = SM[0 .. 2*TM*32), Bs = SM[2*TM*32 ..).
    // For TM=128 the pool is exactly 32KB = the 128x128 bf16 epilogue tile.
    __shared__ u16 SM[2 * TM * 32 + 2 * 128 * 32];
    u16* Asm = SM;
    u16* Bsm = SM + 2 * TM * 32;
    const int tid = threadIdx.x;
    const int w = tid >> 6, lane = tid & 63, ln = lane & 15, qd = lane >> 4;
    const int wr = w >> 1, wc = w & 1;
    const int m0 = blockIdx.y * TM, n0 = blockIdx.x * 128;

    const int srow = tid >> 2, scol = (tid & 3) * 8;
    const u16* Abase = A + (size_t)(m0 + srow) * K + scol;
    const u16* Bbase = B + (size_t)(n0 + srow) * K + scol;

    f32x4 acc[MI][4] = {};
    const int nsteps = K >> 5;

#pragma unroll
    for (int it = 0; it < TM / 64; ++it)
        GL2LDS16(Abase + (size_t)(it * 64) * K, &Asm[(tid + it * 256) * 8]);
#pragma unroll
    for (int it = 0; it < 2; ++it)
        GL2LDS16(Bbase + (size_t)(it * 64) * K, &Bsm[(tid + it * 256) * 8]);

    for (int s = 0; s < nsteps; ++s) {
        const u16* Ab = &Asm[(s & 1) * TM * 32];
        const u16* Bb = &Bsm[(s & 1) * 128 * 32];
        if (s + 1 < nsteps) {
            const int nk = (s + 1) << 5;
            const int nb = (s + 1) & 1;
#pragma unroll
            for (int it = 0; it < TM / 64; ++it)
                GL2LDS16(Abase + (size_t)(it * 64) * K + nk, &Asm[nb * TM * 32 + (tid + it * 256) * 8]);
#pragma unroll
            for (int it = 0; it < 2; ++it)
                GL2LDS16(Bbase + (size_t)(it * 64) * K + nk, &Bsm[nb * 128 * 32 + (tid + it * 256) * 8]);
            if constexpr (TM == 128) SYNC_VM(4); else SYNC_VM(3);
        } else {
            SYNC_VM(0);
        }

        bf16x8 af[MI], bfr[4];
#pragma unroll
        for (int i = 0; i < MI; ++i)
            af[i] = *(const bf16x8*)&Ab[(wr * (TM / 2) + i * 16 + ln) * 32 + qd * 8];
#pragma unroll
        for (int j = 0; j < 4; ++j)
            bfr[j] = *(const bf16x8*)&Bb[(wc * 64 + j * 16 + ln) * 32 + qd * 8];
        __builtin_amdgcn_s_setprio(1);
#pragma unroll
        for (int i = 0; i < MI; ++i)
#pragma unroll
            for (int j = 0; j < 4; ++j) {
                if constexpr (SWAP)
                    acc[i][j] = __builtin_amdgcn_mfma_f32_16x16x32_bf16(bfr[j], af[i], acc[i][j], 0, 0, 0);
                else
                    acc[i][j] = __builtin_amdgcn_mfma_f32_16x16x32_bf16(af[i], bfr[j], acc[i][j], 0, 0, 0);
            }
        __builtin_amdgcn_s_setprio(0);
        BAR();
    }

    if constexpr (FUSE_VT) {
        // ---- LDS-transpose epilogue for coalesced VtG stores (old orientation) ----
        const int bq = m0 >> 11;
        BAR_DS();                      // drain all ds_reads of staging data
#pragma unroll
        for (int i = 0; i < MI; ++i)
#pragma unroll
            for (int j = 0; j < 4; ++j) {
                int col = wc * 64 + j * 16 + ln;
                int row0 = wr * 64 + i * 16 + qd * 4;
                int pr = row0 ^ (((col >> 2) & 3) << 4);
                u16x4 ov;
                ov.x = f2bf(acc[i][j][0]); ov.y = f2bf(acc[i][j][1]);
                ov.z = f2bf(acc[i][j][2]); ov.w = f2bf(acc[i][j][3]);
                *(u16x4*)&SM[col * 128 + pr] = ov;
            }
        BAR_DS();                      // writes visible before cross-wave reads
#pragma unroll
        for (int p = 0; p < 8; ++p) {
            int flat = p * 2048 + tid * 8;
            int colL = flat >> 7, rowL = flat & 127;
            int pr = rowL ^ (((colL >> 2) & 3) << 4);
            u16x8 v = *(const u16x8*)&SM[colL * 128 + pr];
            int d = n0 + colL;         // B pre-offset: n0 local in [0,1024)
            int vrow = (bq * 16 + (d >> 6)) * 64 + (d & 63);
            *(u16x8*)&VtG[(size_t)vrow * 2048 + (m0 & 2047) + rowL] = v;
        }
        return;
    }

    if constexpr (SWAP) {
        // swapped output: row = ...+ln, col = ...+qd*4+{0..3} -> packed stores
#pragma unroll
        for (int i = 0; i < MI; ++i)
#pragma unroll
            for (int j = 0; j < 4; ++j) {
                int row = m0 + wr * (TM / 2) + i * 16 + ln;
                int col = n0 + wc * 64 + j * 16 + qd * 4;
                if constexpr (OUT_BF16) {
                    u16x4 ov;
                    ov.x = f2bf(acc[i][j][0]); ov.y = f2bf(acc[i][j][1]);
                    ov.z = f2bf(acc[i][j][2]); ov.w = f2bf(acc[i][j][3]);
                    *(u16x4*)&((u16*)Cout)[(size_t)row * N + col] = ov;
                } else {
                    *(f32x4*)&((float*)Cout)[(size_t)row * N + col] = acc[i][j];
                }
            }
    } else {
#pragma unroll
        for (int i = 0; i < MI; ++i)
#pragma unroll
            for (int j = 0; j < 4; ++j)
#pragma unroll
                for (int r = 0; r < 4; ++r) {
                    int row = m0 + wr * (TM / 2) + i * 16 + qd * 4 + r;
                    int col = n0 + wc * 64 + j * 16 + ln;
                    float v = acc[i][j][r];
                    if constexpr (OUT_BF16)
                        ((u16*)Cout)[(size_t)row * N + col] = f2bf(v);
                    else
                        ((float*)Cout)[(size_t)row * N + col] = v;
                }
    }
}

// ---------- flash attention (causal): R10 exact (best measured: 45.8us) ----------
// Uniform pairs (t,63-t) of 32-row q-tiles, waves 0-1 heavy / 2-3 light, 1024
// blocks, GL2LDS double-buffered K/V, XOR-swizzled LDS, transposed scores,
// no-max exp2 softmax, T5 setprio. pi-permuted K staging (LDS row
// (h,Q1,Q0,r1,r0) <- key (Q1,Q0,h,r1,r0)) makes the PV B-frag materialize
// directly in score registers: zero P LDS traffic, zero cross-lane ops, 0 bank
// conflicts, 44 VGPR. R11 lesson: helper-wave variants cost +36 VGPR and lose
// 23us to occupancy — this kernel lives at <=48 VGPR.
__global__ __launch_bounds__(256) void attn_kernel(const u16* __restrict__ QKV,
                                                   const u16* __restrict__ VtG,
                                                   u16* __restrict__ AO) {
    __shared__ u16 Ks[2][64 * 64];     // [stored-key(pi-permuted)][dh], swizzled
    __shared__ u16 Vts[2][64 * 64];    // [dh][key natural], swizzled

    const int tid = threadIdx.x;
    const int w = tid >> 6, lane = tid & 63, ln = lane & 15, qd = lane >> 4;
    const int b = blockIdx.z, h = blockIdx.y;
    const int t = blockIdx.x;              // pair index 0..31 (heavy-first order)
    const int tH = 63 - t, tL = t;         // 32-row q tiles
    const int tile = (w < 2) ? tH : tL;
    const int myq = tile * 32 + (w & 1) * 16 + ln;
    const int bh = b * 16 + h;
    const int swz = ln & 7;
    const int nchH = (tH >> 1) + 1;        // 17..32
    const int mynch = (tile >> 1) + 1;     // chunks this wave is active for

    // staging: LDS slot row = sr0 (0..31 per instr), swizzled source colgroup.
    // K source row = pi(sr0): LDS row (h,Q1,Q0,r1,r0) <- key (Q1,Q0,h,r1,r0).
    const int sr0 = tid >> 3;
    const int srP = ((sr0 >> 2) & 3) * 8 + ((sr0 >> 4) & 1) * 4 + (sr0 & 3);
    const int sg = (tid & 7) ^ (sr0 & 7);
    const u16* ksrc = QKV + (size_t)(b * 2048 + srP) * 3072 + 1024 + h * 64 + sg * 8;
    const u16* vsrc = VtG + (size_t)(bh * 64 + sr0) * 2048 + sg * 8;

    GL2LDS16(ksrc, &Ks[0][tid * 8]);
    GL2LDS16(ksrc + (size_t)32 * 3072, &Ks[0][tid * 8 + 2048]);
    GL2LDS16(vsrc, &Vts[0][tid * 8]);
    GL2LDS16(vsrc + (size_t)32 * 2048, &Vts[0][tid * 8 + 2048]);

    // Q B-frags, scale*log2e folded in
    const u16* qp = QKV + (size_t)(b * 2048 + myq) * 3072 + h * 64;
    bf16x8 qf0 = scale_frag(*(const bf16x8*)(qp + qd * 8));
    bf16x8 qf1 = scale_frag(*(const bf16x8*)(qp + 32 + qd * 8));

    f32x4 o[4] = {};
    float l = 0.f;

    for (int c = 0; c < nchH; ++c) {
        if (c + 1 < nchH) {
            const int k1 = (c + 1) * 64;
            const int nb = (c + 1) & 1;
            GL2LDS16(ksrc + (size_t)k1 * 3072, &Ks[nb][tid * 8]);
            GL2LDS16(ksrc + (size_t)(k1 + 32) * 3072, &Ks[nb][tid * 8 + 2048]);
            GL2LDS16(vsrc + k1, &Vts[nb][tid * 8]);
            GL2LDS16(vsrc + k1 + 32 * 2048, &Vts[nb][tid * 8 + 2048]);
            SYNC_VM(4);
        } else {
            SYNC_VM(0);
        }

        if (c < mynch) {
            const u16* Kb = Ks[c & 1];
            const u16* Vb = Vts[c & 1];

            // ---- S^T = K Q^T (rows = pi-permuted keys) ----
            f32x4 s[4];
            __builtin_amdgcn_s_setprio(1);
#pragma unroll
            for (int kt = 0; kt < 4; ++kt) {
                const u16* kr = Kb + (kt * 16 + ln) * 64;
                bf16x8 kf0 = *(const bf16x8*)(kr + ((qd ^ swz) * 8));
                bf16x8 kf1 = *(const bf16x8*)(kr + (((qd + 4) ^ swz) * 8));
                f32x4 z = {0.f, 0.f, 0.f, 0.f};
                z = __builtin_amdgcn_mfma_f32_16x16x32_bf16(kf0, qf0, z, 0, 0, 0);
                z = __builtin_amdgcn_mfma_f32_16x16x32_bf16(kf1, qf1, z, 0, 0, 0);
                s[kt] = z;
            }
            __builtin_amdgcn_s_setprio(0);

            // ---- causal mask (diagonal chunk only), permuted key identity ----
            if (c == mynch - 1) {
#pragma unroll
                for (int kt = 0; kt < 4; ++kt)
#pragma unroll
                    for (int r = 0; r < 4; ++r) {
                        int key = c * 64 + 32 * (kt >> 1) + 8 * qd + 4 * (kt & 1) + r;
                        if (key > myq) s[kt][r] = -1e30f;
                    }
            }

            // ---- exp2 + pack DIRECTLY into PV B-frags (zero LDS / cross-lane) ----
            bf16x8 pf0, pf1;
#pragma unroll
            for (int kt = 0; kt < 4; ++kt)
#pragma unroll
                for (int r = 0; r < 4; ++r) {
                    float p = fast_exp2(s[kt][r]);
                    l += p;
                    if (kt < 2) pf0[(kt & 1) * 4 + r] = (__bf16)p;
                    else        pf1[(kt & 1) * 4 + r] = (__bf16)p;
                }

            // ---- PV (V natural key order) ----
            __builtin_amdgcn_s_setprio(1);
#pragma unroll
            for (int dt = 0; dt < 4; ++dt) {
                const u16* vr = Vb + (dt * 16 + ln) * 64;
                bf16x8 vf0 = *(const bf16x8*)(vr + ((qd ^ swz) * 8));
                bf16x8 vf1 = *(const bf16x8*)(vr + (((qd + 4) ^ swz) * 8));
                o[dt] = __builtin_amdgcn_mfma_f32_16x16x32_bf16(vf0, pf0, o[dt], 0, 0, 0);
                o[dt] = __builtin_amdgcn_mfma_f32_16x16x32_bf16(vf1, pf1, o[dt], 0, 0, 0);
            }
            __builtin_amdgcn_s_setprio(0);
        }
        BAR();
    }

    // ---- deferred l reduction, normalize, packed stores ----
    l += __shfl_xor(l, 16); l += __shfl_xor(l, 32);
    float inv = 1.0f / l;
#pragma unroll
    for (int dt = 0; dt < 4; ++dt) {
        uint2 ov = {pack2bf(o[dt][0] * inv, o[dt][1] * inv),
                    pack2bf(o[dt][2] * inv, o[dt][3] * inv)};
        *(uint2*)&AO[(size_t)(b * 2048 + myq) * 1024 + h * 64 + dt * 16 + qd * 4] = ov;
    }
}

// ---------- launch ----------
extern "C" void kernel_launch(void* const* d_in, const int* in_sizes, int n_in,
                              void* d_out, int out_size, void* d_ws, size_t ws_size,
                              hipStream_t stream) {
    const float* x   = (const float*)d_in[0];   // [2,2048,1024]
    const float* qkv = (const float*)d_in[1];   // [3072,1024]
    const float* wo  = (const float*)d_in[2];   // [1024,1024]
    float* out = (float*)d_out;                 // [2,2048,1024] fp32

    char* ws = (char*)d_ws;
    u16* xb    = (u16*)(ws + 0);            //  8 MB : x bf16 [4096,1024]
    u16* qkvb  = (u16*)(ws + 8388608);      //  6 MB : qkv bf16 [3072,1024]
    u16* wob   = (u16*)(ws + 14680064);     //  2 MB : wo bf16 [1024,1024]
    u16* QKVo  = (u16*)(ws + 16777216);     // 24 MB : QKV bf16 (V-cols unwritten)
    u16* AO    = (u16*)(ws + 41943040);     //  8 MB : attn out [4096,1024]
    u16* VtG   = (u16*)(ws + 50331648);     //  8 MB : V^T [2*16*64, 2048]

    convert_all_kernel<<<8192, 256, 0, stream>>>(x, qkv, wo, xb);

    // gemm1 split: QK columns (swapped MFMA -> packed u16x4 C stores) ...
    gemm_bt<128, true, false, true><<<dim3(16, 32), 256, 0, stream>>>(
        xb, qkvb, QKVo, nullptr, 4096, 3072, 1024);
    // ... and V columns (B pre-offset 2048 rows; old orientation + R9 LDS
    // transpose epilogue writing only VtG).
    gemm_bt<128, true, true, false><<<dim3(8, 32), 256, 0, stream>>>(
        xb, qkvb + (size_t)2048 * 1024, nullptr, VtG, 4096, 3072, 1024);

    attn_kernel<<<dim3(32, 16, 2), 256, 0, stream>>>(QKVo, VtG, AO);

    gemm_bt<64, false, false, true><<<dim3(8, 64), 256, 0, stream>>>(
        AO, wob, out, nullptr, 4096, 1024, 1024);
}